// Round 9
// baseline (61.023 us; speedup 1.0000x reference)
//
#include <hip/hip_runtime.h>

// MSCA fused multi-scale depthwise conv chain, one workgroup per (b,c) plane.
// x:[8,256,64,64] f32 -> (attn_0, attn_1, attn_2) each [8,256,64,64] f32.
//
// R8 = R7 minus the x-LDS staging: the 5x5 conv reads x directly from global
// (rows are L2-hot; 5 coalesced row-loads per thread, row-edge zeros via
// clamp+select BEFORE the DPP col-halo, which is mask-safe because in-strip
// neighbors share maj). Kills barrier B1, the X LDS region, and 15 of 25
// ds_read_b128 per thread. Everything else is R7 verbatim.
//
// 512 threads/block, 8 px/thread, strips of 8; halos via DPP row_shr/shl 1,2
// (hoisted, then selected); 8-lane strip seams == image edges.
// X-role: row=maj, cols [8*lane8,+8). T-role: col=maj, rows [8*lane8,+8).
// Transpose involution swizzle: minor' = minor ^ (strip<<3):
//   write:  buf[(8*lane8+e)*68 + (maj ^ (lane8<<3))]
//   read :  buf[maj*68 + ((lane8 ^ ((maj>>3)&7))<<3) + e]   (2x b128, aligned)
// Liveness: RA: Y0 -> Y2 ; RB: ATT_T -> Y1. 4 barriers.
// o0 stored at start of P4, o1/o2 in P5 (drain under compute).

#define RW 4352                    // 64*68
#define LDS_WORDS (2 * RW)         // 8704 words = 34816 B

__device__ __forceinline__ float dppsr1(float v) {   // lane i <- i-1 (16-lane rows)
    return __int_as_float(__builtin_amdgcn_update_dpp(
        0, __float_as_int(v), 0x111, 0xF, 0xF, false));
}
__device__ __forceinline__ float dppsr2(float v) {   // lane i <- i-2
    return __int_as_float(__builtin_amdgcn_update_dpp(
        0, __float_as_int(v), 0x112, 0xF, 0xF, false));
}
__device__ __forceinline__ float dppsl1(float v) {   // lane i <- i+1
    return __int_as_float(__builtin_amdgcn_update_dpp(
        0, __float_as_int(v), 0x101, 0xF, 0xF, false));
}
__device__ __forceinline__ float dppsl2(float v) {   // lane i <- i+2
    return __int_as_float(__builtin_amdgcn_update_dpp(
        0, __float_as_int(v), 0x102, 0xF, 0xF, false));
}
__device__ __forceinline__ void ld8(const float* p, float* d) {
    float4 a = *(const float4*)p, b = *(const float4*)(p + 4);
    d[0]=a.x; d[1]=a.y; d[2]=a.z; d[3]=a.w; d[4]=b.x; d[5]=b.y; d[6]=b.z; d[7]=b.w;
}
__device__ __forceinline__ void st8(float* p, const float* d) {
    float4 a, b;
    a.x=d[0]; a.y=d[1]; a.z=d[2]; a.w=d[3]; b.x=d[4]; b.y=d[5]; b.z=d[6]; b.w=d[7];
    *(float4*)p = a; *(float4*)(p + 4) = b;
}

// Accumulate window part: src[i] sits at window position W0+i (N elements).
// acc[j] += wt[v]*window[j+v] for all in-range terms. All indices static.
template<int K, int W0, int N>
__device__ __forceinline__ void cpart(const float* __restrict__ wt,
                                      const float* s, float* acc) {
    #pragma unroll
    for (int v = 0; v < K; v++) {
        #pragma unroll
        for (int j = 0; j < 8; j++) {
            const int p = j + v - W0;
            if (p >= 0 && p < N) acc[j] += wt[v] * s[p];
        }
    }
}

// Strip conv, K=2H+1 taps, H<=8: halo from lane+-1 (DPP hoisted, select after).
template<int H>
__device__ __forceinline__ void sconv(const float* __restrict__ wt, float bb,
                                      const float* a, bool pm, bool np, float* acc) {
    constexpr int K = 2 * H + 1;
    float pv[H], nv[H];
    #pragma unroll
    for (int i = 0; i < H; i++) pv[i] = dppsr1(a[8 - H + i]);
    #pragma unroll
    for (int i = 0; i < H; i++) nv[i] = dppsl1(a[i]);
    #pragma unroll
    for (int i = 0; i < H; i++) pv[i] = pm ? pv[i] : 0.f;
    #pragma unroll
    for (int i = 0; i < H; i++) nv[i] = np ? nv[i] : 0.f;
    #pragma unroll
    for (int j = 0; j < 8; j++) acc[j] = bb;
    cpart<K, 0, H>(wt, pv, acc);
    cpart<K, H, 8>(wt, a, acc);
    cpart<K, H + 8, H>(wt, nv, acc);
}

// 21-tap strip conv (H=10): halo spans lane+-1 (8) and lane+-2 (2).
__device__ __forceinline__ void sconv21(const float* __restrict__ wt, float bb,
                                        const float* a, bool pm, bool pm2,
                                        bool np, bool np2, float* acc) {
    #pragma unroll
    for (int j = 0; j < 8; j++) acc[j] = bb;
    {
        float q[2];
        q[0] = dppsr2(a[6]); q[1] = dppsr2(a[7]);
        q[0] = pm2 ? q[0] : 0.f; q[1] = pm2 ? q[1] : 0.f;
        cpart<21, 0, 2>(wt, q, acc);
    }
    {
        float pv[8];
        #pragma unroll
        for (int i = 0; i < 8; i++) pv[i] = dppsr1(a[i]);
        #pragma unroll
        for (int i = 0; i < 8; i++) pv[i] = pm ? pv[i] : 0.f;
        cpart<21, 2, 8>(wt, pv, acc);
    }
    cpart<21, 10, 8>(wt, a, acc);
    {
        float nv[8];
        #pragma unroll
        for (int i = 0; i < 8; i++) nv[i] = dppsl1(a[i]);
        #pragma unroll
        for (int i = 0; i < 8; i++) nv[i] = np ? nv[i] : 0.f;
        cpart<21, 18, 8>(wt, nv, acc);
    }
    {
        float q[2];
        q[0] = dppsl2(a[0]); q[1] = dppsl2(a[1]);
        q[0] = np2 ? q[0] : 0.f; q[1] = np2 ? q[1] : 0.f;
        cpart<21, 26, 2>(wt, q, acc);
    }
}

__global__ __launch_bounds__(512, 8)
void msca_fused(const float* __restrict__ x,
                const float* __restrict__ w0,   const float* __restrict__ b0,
                const float* __restrict__ w0_1, const float* __restrict__ b0_1,
                const float* __restrict__ w0_2, const float* __restrict__ b0_2,
                const float* __restrict__ w1_1, const float* __restrict__ b1_1,
                const float* __restrict__ w1_2, const float* __restrict__ b1_2,
                const float* __restrict__ w2_1, const float* __restrict__ b2_1,
                const float* __restrict__ w2_2, const float* __restrict__ b2_2,
                float* __restrict__ out)
{
    __shared__ __align__(16) float lds[LDS_WORDS];
    float* RA = lds;            // Y0 -> Y2
    float* RB = lds + RW;       // ATT_T -> Y1

    const int t     = threadIdx.x;     // 0..511
    const int maj   = t >> 3;          // X: image row r ; T: image col c
    const int lane8 = t & 7;           // X: col-strip ; T: row-strip
    const int j0    = lane8 << 3;

    const bool pm  = lane8 >= 1, np  = lane8 <= 6;
    const bool pm2 = lane8 >= 2, np2 = lane8 <= 5;

    const int scat = maj ^ (lane8 << 3);                           // scatter minor
    const int rdb  = maj * 68 + ((lane8 ^ ((maj >> 3) & 7)) << 3); // strip read base

    const int plane = blockIdx.x;
    const int ch    = plane & 255;

    const float* xg = x + (size_t)plane * 4096;
    float* o0 = out + (size_t)plane * 4096;
    float* o1 = o0 + 8388608;
    float* o2 = o1 + 8388608;

    // ---- P1: attn = conv5x5(x)+b0, x read DIRECT from global (L2-hot) ----
    float attn[8];
    {
        const float bb = b0[ch];
        #pragma unroll
        for (int j = 0; j < 8; j++) attn[j] = bb;
        const float* w0p = w0 + ch * 25;
        #pragma unroll
        for (int dr = 0; dr < 5; dr++) {
            const int ri = maj + dr - 2;
            const int rc = ri < 0 ? 0 : (ri > 63 ? 63 : ri);
            const bool valid = (unsigned)ri <= 63u;
            float a[8];
            ld8(&xg[rc * 64 + j0], a);
            #pragma unroll
            for (int i = 0; i < 8; i++) a[i] = valid ? a[i] : 0.f;  // row-edge zero
            // col halo +-2 via DPP (in-strip neighbors share maj -> safe)
            float l0 = dppsr1(a[6]), l1 = dppsr1(a[7]);
            float r0 = dppsl1(a[0]), r1 = dppsl1(a[1]);
            float wnd[12];
            wnd[0] = pm ? l0 : 0.f;  wnd[1] = pm ? l1 : 0.f;
            #pragma unroll
            for (int i = 0; i < 8; i++) wnd[2 + i] = a[i];
            wnd[10] = np ? r0 : 0.f; wnd[11] = np ? r1 : 0.f;
            #pragma unroll
            for (int v = 0; v < 5; v++) {
                const float ww = w0p[dr * 5 + v];
                #pragma unroll
                for (int j = 0; j < 8; j++) attn[j] += ww * wnd[j + v];
            }
        }
        #pragma unroll
        for (int e = 0; e < 8; e++) RB[(j0 + e) * 68 + scat] = attn[e];  // ATT_T
    }
    __syncthreads();   // B2  (ATT_T ready)

    // ---- P2: a0x (X-role); read attn T-strip; a0y (T-role); scatter Y0 ----
    float a0x[8];
    sconv<3>(w0_1 + ch * 7, b0_1[ch], attn, pm, np, a0x);
    float stv[8];
    ld8(&RB[rdb], stv);
    float aty0[8];
    sconv<3>(w0_2 + ch * 7, b0_2[ch], stv, pm, np, aty0);   // strip masks == edges
    #pragma unroll
    for (int d = 0; d < 8; d++) RA[(j0 + d) * 68 + scat] = aty0[d];   // Y0
    __syncthreads();   // B3  (Y0 ready; ATT_T reads done)

    // ---- P3: prod0 = a0x*Y0row; a1x; a1y (T); scatter Y1 ----
    float prod0[8];
    {
        float y0r[8];
        ld8(&RA[rdb], y0r);
        #pragma unroll
        for (int j = 0; j < 8; j++) prod0[j] = a0x[j] * y0r[j];
    }
    float a1x[8];
    sconv<5>(w1_1 + ch * 11, b1_1[ch], a0x, pm, np, a1x);
    float aty1[8];
    sconv<5>(w1_2 + ch * 11, b1_2[ch], aty0, pm, np, aty1);
    #pragma unroll
    for (int d = 0; d < 8; d++) RB[(j0 + d) * 68 + scat] = aty1[d];   // Y1
    __syncthreads();   // B4  (Y1 ready; Y0 reads done)

    // ---- P4: store o0; prod1 = a1x*Y1row; a2y (T) -> Y2; a2x ----
    st8(&o0[maj * 64 + j0], prod0);
    float prod1[8];
    {
        float y1r[8];
        ld8(&RB[rdb], y1r);
        #pragma unroll
        for (int j = 0; j < 8; j++) prod1[j] = a1x[j] * y1r[j];
    }
    {
        float a2y[8];
        sconv21(w2_2 + ch * 21, b2_2[ch], aty1, pm, pm2, np, np2, a2y);
        #pragma unroll
        for (int d = 0; d < 8; d++) RA[(j0 + d) * 68 + scat] = a2y[d]; // Y2
    }
    float a2x[8];
    sconv21(w2_1 + ch * 21, b2_1[ch], a1x, pm, pm2, np, np2, a2x);
    __syncthreads();   // B5  (Y2 ready; o0 drained under P4 compute)

    // ---- P5: store o1; prod2 = a2x*Y2row; store o2 ----
    st8(&o1[maj * 64 + j0], prod1);
    {
        float y2r[8], prod2[8];
        ld8(&RA[rdb], y2r);
        #pragma unroll
        for (int j = 0; j < 8; j++) prod2[j] = a2x[j] * y2r[j];
        st8(&o2[maj * 64 + j0], prod2);
    }
}

extern "C" void kernel_launch(void* const* d_in, const int* in_sizes, int n_in,
                              void* d_out, int out_size, void* d_ws, size_t ws_size,
                              hipStream_t stream) {
    msca_fused<<<2048, 512, 0, stream>>>(
        (const float*)d_in[0],
        (const float*)d_in[1],  (const float*)d_in[2],
        (const float*)d_in[3],  (const float*)d_in[4],
        (const float*)d_in[5],  (const float*)d_in[6],
        (const float*)d_in[7],  (const float*)d_in[8],
        (const float*)d_in[9],  (const float*)d_in[10],
        (const float*)d_in[11], (const float*)d_in[12],
        (const float*)d_in[13], (const float*)d_in[14],
        (float*)d_out);
}

// Round 10
// 42.984 us; speedup vs baseline: 1.4197x; 1.4197x over previous
//
#include <hip/hip_runtime.h>

// MSCA fused multi-scale depthwise conv chain, one workgroup per (b,c) plane.
// x:[8,256,64,64] f32 -> (attn_0, attn_1, attn_2) each [8,256,64,64] f32.
//
// R9 = R7 verbatim with __launch_bounds__(512,4) (VGPR cap 128, not 64).
// R8's counters (VGPR=32, VALUBusy 1.8%, WRITE 192MB=out+spill, FETCH 64MB)
// showed the (512,8) bound forced scratch spills; this relaxes it. LDS x
// staging restored (R8's direct-global x read thrashed L2 on top of spills).
//
// 512 threads/block, 8 px/thread, 36KB LDS; strips of 8; halos via DPP
// row_shr/shl 1,2 (hoisted, then selected); 8-lane strip seams == image edges.
// X-role: row=maj, cols [8*lane8,+8). T-role: col=maj, rows [8*lane8,+8).
// Transpose involution swizzle: minor' = minor ^ (strip<<3):
//   write:  buf[(8*lane8+e)*68 + (maj ^ (lane8<<3))]
//   read :  buf[maj*68 + ((lane8 ^ ((maj>>3)&7))<<3) + e]   (2x b128, aligned)
// Liveness: RA: X(68x68,+-2 halo) -> Y0 -> Y2 ; RB: ATT_T -> Y1. 5 barriers.
// o0 stored at start of P4, o1/o2 in P5 (drain under compute).

#define RA_W 4624                  // 68*68
#define RB_W 4352                  // 64*68
#define LDS_WORDS (RA_W + RB_W)    // 8976 words = 35904 B

__device__ __forceinline__ float dppsr1(float v) {   // lane i <- i-1 (16-lane rows)
    return __int_as_float(__builtin_amdgcn_update_dpp(
        0, __float_as_int(v), 0x111, 0xF, 0xF, false));
}
__device__ __forceinline__ float dppsr2(float v) {   // lane i <- i-2
    return __int_as_float(__builtin_amdgcn_update_dpp(
        0, __float_as_int(v), 0x112, 0xF, 0xF, false));
}
__device__ __forceinline__ float dppsl1(float v) {   // lane i <- i+1
    return __int_as_float(__builtin_amdgcn_update_dpp(
        0, __float_as_int(v), 0x101, 0xF, 0xF, false));
}
__device__ __forceinline__ float dppsl2(float v) {   // lane i <- i+2
    return __int_as_float(__builtin_amdgcn_update_dpp(
        0, __float_as_int(v), 0x102, 0xF, 0xF, false));
}
__device__ __forceinline__ void ld8(const float* p, float* d) {
    float4 a = *(const float4*)p, b = *(const float4*)(p + 4);
    d[0]=a.x; d[1]=a.y; d[2]=a.z; d[3]=a.w; d[4]=b.x; d[5]=b.y; d[6]=b.z; d[7]=b.w;
}
__device__ __forceinline__ void st8(float* p, const float* d) {
    float4 a, b;
    a.x=d[0]; a.y=d[1]; a.z=d[2]; a.w=d[3]; b.x=d[4]; b.y=d[5]; b.z=d[6]; b.w=d[7];
    *(float4*)p = a; *(float4*)(p + 4) = b;
}

// Accumulate window part: src[i] sits at window position W0+i (N elements).
// acc[j] += wt[v]*window[j+v] for all in-range terms. All indices static.
template<int K, int W0, int N>
__device__ __forceinline__ void cpart(const float* __restrict__ wt,
                                      const float* s, float* acc) {
    #pragma unroll
    for (int v = 0; v < K; v++) {
        #pragma unroll
        for (int j = 0; j < 8; j++) {
            const int p = j + v - W0;
            if (p >= 0 && p < N) acc[j] += wt[v] * s[p];
        }
    }
}

// Strip conv, K=2H+1 taps, H<=8: halo from lane+-1 (DPP hoisted, select after).
template<int H>
__device__ __forceinline__ void sconv(const float* __restrict__ wt, float bb,
                                      const float* a, bool pm, bool np, float* acc) {
    constexpr int K = 2 * H + 1;
    float pv[H], nv[H];
    #pragma unroll
    for (int i = 0; i < H; i++) pv[i] = dppsr1(a[8 - H + i]);
    #pragma unroll
    for (int i = 0; i < H; i++) nv[i] = dppsl1(a[i]);
    #pragma unroll
    for (int i = 0; i < H; i++) pv[i] = pm ? pv[i] : 0.f;
    #pragma unroll
    for (int i = 0; i < H; i++) nv[i] = np ? nv[i] : 0.f;
    #pragma unroll
    for (int j = 0; j < 8; j++) acc[j] = bb;
    cpart<K, 0, H>(wt, pv, acc);
    cpart<K, H, 8>(wt, a, acc);
    cpart<K, H + 8, H>(wt, nv, acc);
}

// 21-tap strip conv (H=10): halo spans lane+-1 (8) and lane+-2 (2).
__device__ __forceinline__ void sconv21(const float* __restrict__ wt, float bb,
                                        const float* a, bool pm, bool pm2,
                                        bool np, bool np2, float* acc) {
    #pragma unroll
    for (int j = 0; j < 8; j++) acc[j] = bb;
    {
        float q[2];
        q[0] = dppsr2(a[6]); q[1] = dppsr2(a[7]);
        q[0] = pm2 ? q[0] : 0.f; q[1] = pm2 ? q[1] : 0.f;
        cpart<21, 0, 2>(wt, q, acc);
    }
    {
        float pv[8];
        #pragma unroll
        for (int i = 0; i < 8; i++) pv[i] = dppsr1(a[i]);
        #pragma unroll
        for (int i = 0; i < 8; i++) pv[i] = pm ? pv[i] : 0.f;
        cpart<21, 2, 8>(wt, pv, acc);
    }
    cpart<21, 10, 8>(wt, a, acc);
    {
        float nv[8];
        #pragma unroll
        for (int i = 0; i < 8; i++) nv[i] = dppsl1(a[i]);
        #pragma unroll
        for (int i = 0; i < 8; i++) nv[i] = np ? nv[i] : 0.f;
        cpart<21, 18, 8>(wt, nv, acc);
    }
    {
        float q[2];
        q[0] = dppsl2(a[0]); q[1] = dppsl2(a[1]);
        q[0] = np2 ? q[0] : 0.f; q[1] = np2 ? q[1] : 0.f;
        cpart<21, 26, 2>(wt, q, acc);
    }
}

__global__ __launch_bounds__(512, 4)
void msca_fused(const float* __restrict__ x,
                const float* __restrict__ w0,   const float* __restrict__ b0,
                const float* __restrict__ w0_1, const float* __restrict__ b0_1,
                const float* __restrict__ w0_2, const float* __restrict__ b0_2,
                const float* __restrict__ w1_1, const float* __restrict__ b1_1,
                const float* __restrict__ w1_2, const float* __restrict__ b1_2,
                const float* __restrict__ w2_1, const float* __restrict__ b2_1,
                const float* __restrict__ w2_2, const float* __restrict__ b2_2,
                float* __restrict__ out)
{
    __shared__ __align__(16) float lds[LDS_WORDS];
    float* RA = lds;            // X (68x68, +-2 halo) -> Y0 -> Y2
    float* RB = lds + RA_W;     // ATT_T -> Y1

    const int t     = threadIdx.x;     // 0..511
    const int maj   = t >> 3;          // X: image row r ; T: image col c
    const int lane8 = t & 7;           // X: col-strip ; T: row-strip
    const int j0    = lane8 << 3;

    const bool pm  = lane8 >= 1, np  = lane8 <= 6;
    const bool pm2 = lane8 >= 2, np2 = lane8 <= 5;

    const int scat = maj ^ (lane8 << 3);                           // scatter minor
    const int rdb  = maj * 68 + ((lane8 ^ ((maj >> 3) & 7)) << 3); // strip read base

    const int plane = blockIdx.x;
    const int ch    = plane & 255;

    const float* xg = x + (size_t)plane * 4096;
    float* o0 = out + (size_t)plane * 4096;
    float* o1 = o0 + 8388608;
    float* o2 = o1 + 8388608;

    // ---- stage 0: load x (8 px), zero X halos, commit ----
    float xr[8];
    ld8(&xg[maj * 64 + j0], xr);
    if (t < 136) { RA[t] = 0.f; RA[t + 4488] = 0.f; }        // halo rows 0,1,66,67
    if (t < 256) {                                            // side cols rows 2..65
        int rr = 2 + (t >> 2), cc = t & 3;
        RA[rr * 68 + (cc < 2 ? cc : cc + 64)] = 0.f;
    }
    {
        float* row = &RA[(maj + 2) * 68 + j0 + 2];
        float2 p;
        p.x = xr[0]; p.y = xr[1]; ((float2*)row)[0] = p;
        p.x = xr[2]; p.y = xr[3]; ((float2*)row)[1] = p;
        p.x = xr[4]; p.y = xr[5]; ((float2*)row)[2] = p;
        p.x = xr[6]; p.y = xr[7]; ((float2*)row)[3] = p;
    }
    __syncthreads();   // B1

    // ---- P1: attn = conv5x5(x)+b0 (all rows from LDS); scatter ATT_T ----
    float attn[8];
    {
        const float bb = b0[ch];
        #pragma unroll
        for (int j = 0; j < 8; j++) attn[j] = bb;
        const float* w0p = w0 + ch * 25;
        #pragma unroll
        for (int dr = 0; dr < 5; dr++) {
            float wnd[12];                      // image cols j0-2 .. j0+9
            const float* rowp = &RA[(maj + dr) * 68 + j0];
            float4 qa = *(const float4*)rowp;
            float4 qb = *(const float4*)(rowp + 4);
            float4 qc = *(const float4*)(rowp + 8);
            wnd[0]=qa.x; wnd[1]=qa.y; wnd[2]=qa.z;  wnd[3]=qa.w;
            wnd[4]=qb.x; wnd[5]=qb.y; wnd[6]=qb.z;  wnd[7]=qb.w;
            wnd[8]=qc.x; wnd[9]=qc.y; wnd[10]=qc.z; wnd[11]=qc.w;
            #pragma unroll
            for (int v = 0; v < 5; v++) {
                const float ww = w0p[dr * 5 + v];
                #pragma unroll
                for (int j = 0; j < 8; j++) attn[j] += ww * wnd[j + v];
            }
        }
        #pragma unroll
        for (int e = 0; e < 8; e++) RB[(j0 + e) * 68 + scat] = attn[e];
    }
    __syncthreads();   // B2  (ATT_T ready; X reads done)

    // ---- P2: a0x (X-role); read attn T-strip; a0y (T-role); scatter Y0 ----
    float a0x[8];
    sconv<3>(w0_1 + ch * 7, b0_1[ch], attn, pm, np, a0x);
    float stv[8];
    ld8(&RB[rdb], stv);
    float aty0[8];
    sconv<3>(w0_2 + ch * 7, b0_2[ch], stv, pm, np, aty0);   // s-masks == lane8-masks
    #pragma unroll
    for (int d = 0; d < 8; d++) RA[(j0 + d) * 68 + scat] = aty0[d];   // Y0
    __syncthreads();   // B3  (Y0 ready; ATT_T reads done)

    // ---- P3: prod0 = a0x*Y0row; a1x; a1y (T); scatter Y1 ----
    float prod0[8];
    {
        float y0r[8];
        ld8(&RA[rdb], y0r);
        #pragma unroll
        for (int j = 0; j < 8; j++) prod0[j] = a0x[j] * y0r[j];
    }
    float a1x[8];
    sconv<5>(w1_1 + ch * 11, b1_1[ch], a0x, pm, np, a1x);
    float aty1[8];
    sconv<5>(w1_2 + ch * 11, b1_2[ch], aty0, pm, np, aty1);
    #pragma unroll
    for (int d = 0; d < 8; d++) RB[(j0 + d) * 68 + scat] = aty1[d];   // Y1
    __syncthreads();   // B4  (Y1 ready; Y0 reads done)

    // ---- P4: store o0; prod1 = a1x*Y1row; a2y (T) -> Y2; a2x ----
    st8(&o0[maj * 64 + j0], prod0);
    float prod1[8];
    {
        float y1r[8];
        ld8(&RB[rdb], y1r);
        #pragma unroll
        for (int j = 0; j < 8; j++) prod1[j] = a1x[j] * y1r[j];
    }
    {
        float a2y[8];
        sconv21(w2_2 + ch * 21, b2_2[ch], aty1, pm, pm2, np, np2, a2y);
        #pragma unroll
        for (int d = 0; d < 8; d++) RA[(j0 + d) * 68 + scat] = a2y[d]; // Y2
    }
    float a2x[8];
    sconv21(w2_1 + ch * 21, b2_1[ch], a1x, pm, pm2, np, np2, a2x);
    __syncthreads();   // B5  (Y2 ready; o0 drained under P4 compute)

    // ---- P5: store o1; prod2 = a2x*Y2row; store o2 ----
    st8(&o1[maj * 64 + j0], prod1);
    {
        float y2r[8], prod2[8];
        ld8(&RA[rdb], y2r);
        #pragma unroll
        for (int j = 0; j < 8; j++) prod2[j] = a2x[j] * y2r[j];
        st8(&o2[maj * 64 + j0], prod2);
    }
}

extern "C" void kernel_launch(void* const* d_in, const int* in_sizes, int n_in,
                              void* d_out, int out_size, void* d_ws, size_t ws_size,
                              hipStream_t stream) {
    msca_fused<<<2048, 512, 0, stream>>>(
        (const float*)d_in[0],
        (const float*)d_in[1],  (const float*)d_in[2],
        (const float*)d_in[3],  (const float*)d_in[4],
        (const float*)d_in[5],  (const float*)d_in[6],
        (const float*)d_in[7],  (const float*)d_in[8],
        (const float*)d_in[9],  (const float*)d_in[10],
        (const float*)d_in[11], (const float*)d_in[12],
        (const float*)d_in[13], (const float*)d_in[14],
        (float*)d_out);
}